// Round 8
// baseline (198.914 us; speedup 1.0000x reference)
//
#include <hip/hip_runtime.h>
#include <cstdint>
#include <cstddef>

// CapsuleLayer dynamic routing, MI355X — R8.
// R7 with the cross-lane reduction reverted to __shfl_xor (permlane*_swap
// semantics unverified -> suspected NaN source: wrong d -> expf overflow ->
// inf*0). Shuffle count cut 4->3 per j: xor16 both c's, one xor32 exchange
// carrying the other-c partial; each lane finishes only its OWN c's logit.
// Keeps R7 wins: one b128 W-frag read shared by phases A+B (masked-B MFMA),
// 512 blocks x 512 thr, single W buffer.
// ws: SP 33,554,432 B + v0 262,144 + v01 262,144 = 34,078,720 B.

#define CN     2048
#define JN     32
#define UN     16
#define IN_    16
#define CPB    16            // c's per block
#define PAIRS  (CPB/2)
#define NCHUNK (CN/CPB)      // 128
#define NBG    4             // b-groups of 32

#define WT_PAD 24                       // i-dim pad (48B stride, 16B-aligned)
#define WT_C   (JN*UN*WT_PAD)           // f16 per c = 12288
#define WT_BYTES (2*WT_C*2)             // 49152 (c-pair)
#define LDS_SZ   (WT_BYTES + 2*2*4*16*4) // + psm[2][2][4][16] f32 = 50176

typedef _Float16 f16;
typedef _Float16 f16x2 __attribute__((ext_vector_type(2)));
typedef _Float16 f16x4 __attribute__((ext_vector_type(4)));
typedef _Float16 f16x8 __attribute__((ext_vector_type(8)));
typedef __fp16   h16x2 __attribute__((ext_vector_type(2)));
typedef float    f32x4 __attribute__((ext_vector_type(4)));

static __device__ __forceinline__ f16x2 pkrtz(float a, float b) {
    h16x2 r = __builtin_amdgcn_cvt_pkrtz(a, b);
    return __builtin_bit_cast(f16x2, r);
}
static __device__ __forceinline__ float fdot2(f16x2 a, f16x2 b, float c) {
    return __builtin_amdgcn_fdot2(__builtin_bit_cast(h16x2, a),
                                  __builtin_bit_cast(h16x2, b), c, false);
}
struct P2 { f16x2 a, b; };
static __device__ __forceinline__ f16x4 join2(f16x2 a, f16x2 b) {
    P2 p{a, b};
    return __builtin_bit_cast(f16x4, p);
}
struct P4 { f16x4 a, b; };
static __device__ __forceinline__ f16x8 join4(f16x4 a, f16x4 b) {
    P4 p{a, b};
    return __builtin_bit_cast(f16x8, p);
}

// Stage W c-pair: f32 [j][i][u] -> LDS f16 [cc][j][u][WT_PAD]. 512 thr x 4 slots.
__device__ __forceinline__ void stage_pair(const float* __restrict__ W,
                                           f16* Wt, int c0, int tid)
{
#pragma unroll
    for (int h = 0; h < 4; ++h) {
        const int s  = tid + h*512;
        const int u  = s & 15;
        const int ih = (s >> 4) & 1;
        const int j  = (s >> 5) & 31;
        const int cc = s >> 10;
        const float* src = W + (size_t)(c0+cc)*(JN*IN_*UN) + j*(IN_*UN) + (ih*8)*UN + u;
        f16x8 v;
#pragma unroll
        for (int k = 0; k < 8; ++k) v[k] = (f16)src[k*UN];
        *(f16x8*)(Wt + cc*WT_C + j*(UN*WT_PAD) + u*WT_PAD + ih*8) = v;
    }
}

template<int ROUTED>
__global__ __launch_bounds__(512, 4)
void route_kernel(const float* __restrict__ x, const float* __restrict__ W,
                  const float* __restrict__ v01g, float* __restrict__ SP)
{
    extern __shared__ char smem[];
    f16*   Wt  = (f16*)smem;
    float* psm = (float*)(smem + WT_BYTES);   // [cc 2][btl 2][jq 4][b 16]

    const int tid = threadIdx.x;
    const int l   = tid & 63;
    const int wid = tid >> 6;     // 8 waves
    const int btl = wid & 1;      // b-tile (2 x 16 b)
    const int jq  = wid >> 1;     // j-quarter (8 j's)
    const int g   = l >> 4;       // k-slot group / u-row group
    const int m15 = l & 15;

    const int bid   = blockIdx.x;
    const int bg    = bid & 3;    // b-group of 32
    const int chunk = bid >> 2;   // c-chunk
    const int bl    = btl*16 + m15;
    const int bglob = bg*32 + bl;
    const int cbase = chunk * CPB;
    const int jbase = jq * 8;
    const int ccme  = g >> 1;     // this lane's c within the pair (K=32 packing)

    // v01 for this lane's (b, jq, u=4g..4g+3) -> registers (c-invariant)
    f16x2 vfr[8][2];
    if (ROUTED) {
#pragma unroll
        for (int jj = 0; jj < 8; ++jj) {
            f32x4 vv = *(const f32x4*)(v01g + (size_t)bglob*512 + (jbase+jj)*16 + 4*g);
            vfr[jj][0] = pkrtz(vv[0], vv[1]);
            vfr[jj][1] = pkrtz(vv[2], vv[3]);
        }
    }

    f32x4 acc[8];
#pragma unroll
    for (int jj = 0; jj < 8; ++jj) acc[jj] = (f32x4){0.f,0.f,0.f,0.f};
    const f32x4 zero4 = {0.f,0.f,0.f,0.f};

    stage_pair(W, Wt, cbase, tid);
    __syncthreads();

    for (int p = 0; p < PAIRS; ++p) {
        const int c0 = cbase + 2*p;

        // x for this lane's k-slots: x[b=bglob, c0+ccme, i=8(g&1)..+8]
        const float* xp = x + ((size_t)bglob*CN + (c0 + ccme))*IN_ + (g&1)*8;
        f32x4 xv0 = *(const f32x4*)xp;
        f32x4 xv1 = *(const f32x4*)(xp + 4);
        f16x8 xq = join4(join2(pkrtz(xv0[0], xv0[1]), pkrtz(xv0[2], xv0[3])),
                         join2(pkrtz(xv1[0], xv1[1]), pkrtz(xv1[2], xv1[3])));

        // W fragments for this pair: one b128 read per jj, reused by A and B
        f16x8 wfr[8];
#pragma unroll
        for (int jj = 0; jj < 8; ++jj)
            wfr[jj] = *(const f16x8*)(Wt + ccme*WT_C + (jbase+jj)*(UN*WT_PAD)
                                      + m15*WT_PAD + (g&1)*8);

        float lme[8];
        float myrden = 0.f;
        if (ROUTED) {
            // masked B-operands: keep only c0 (resp. c1) k-slots
            f16x8 xz;
#pragma unroll
            for (int r = 0; r < 8; ++r) xz[r] = (f16)0.f;
            const f16x8 xb0 = (ccme == 0) ? xq : xz;
            const f16x8 xb1 = (ccme == 0) ? xz : xq;

            float summe = 0.f;
#pragma unroll
            for (int jj = 0; jj < 8; ++jj) {
                f32x4 uh0 = __builtin_amdgcn_mfma_f32_16x16x32_f16(wfr[jj], xb0, zero4, 0,0,0);
                float d0 = fdot2(pkrtz(uh0[0], uh0[1]), vfr[jj][0], 0.f);
                d0       = fdot2(pkrtz(uh0[2], uh0[3]), vfr[jj][1], d0);
                f32x4 uh1 = __builtin_amdgcn_mfma_f32_16x16x32_f16(wfr[jj], xb1, zero4, 0,0,0);
                float d1 = fdot2(pkrtz(uh1[0], uh1[1]), vfr[jj][0], 0.f);
                d1       = fdot2(pkrtz(uh1[2], uh1[3]), vfr[jj][1], d1);
                // u-reduction: xor16 both c's, then ONE xor32 exchange that
                // carries the OTHER c's partial; lane finishes only its own c.
                float t0 = d0 + __shfl_xor(d0, 16);
                float t1 = d1 + __shfl_xor(d1, 16);
                float sown = (ccme == 0) ? t0 : t1;
                float soth = (ccme == 0) ? t1 : t0;
                float dme  = sown + __shfl_xor(soth, 32);
                float e = __expf(dme);            // no max-sub: |logit| << 88
                summe += e;
                lme[jj] = e;
            }
            // g==0 lanes write c0 sums, g==2 lanes write c1 sums
            if ((l & 31) < 16)
                psm[(ccme*2+btl)*64 + jq*16 + m15] = summe;
            __syncthreads();                      // psm ready
            {
                const float* pp = psm + (ccme*2+btl)*64 + m15;
                myrden = 1.f / (pp[0] + pp[16] + pp[32] + pp[48]);
            }
        }

        // ---- phase B: s_j += c_ij * u_hat (c-pair packed K=32) ----
#pragma unroll
        for (int jj = 0; jj < 8; ++jj) {
            f16x8 bx = xq;
            if (ROUTED) {
                const f16 hsc = (f16)(lme[jj] * myrden);
#pragma unroll
                for (int r = 0; r < 8; ++r) bx[r] = xq[r] * hsc;   // v_pk_mul_f16
            }
            acc[jj] = __builtin_amdgcn_mfma_f32_16x16x32_f16(wfr[jj], bx, acc[jj], 0,0,0);
        }

        __syncthreads();                          // Wt consumed
        if (p + 1 < PAIRS) stage_pair(W, Wt, c0 + 2, tid);
        __syncthreads();                          // Wt ready
    }

    // partial s: SP[(bg*128+chunk)*32 + bl][j 32][u 16] f32
    float* dst = SP + (((size_t)(bg*NCHUNK + chunk))*32 + bl)*512;
#pragma unroll
    for (int jj = 0; jj < 8; ++jj)
        *(f32x4*)(dst + (jbase+jj)*16 + 4*g) = acc[jj];
}

// Reduce 128 chunk-partials, squash over J. grid 128 (b), block 512 (tid=j*16+u).
__global__ __launch_bounds__(512)
void squash_kernel(const float* __restrict__ SP, float* __restrict__ v0buf,
                   float* __restrict__ v01buf, float* __restrict__ outp, int mode)
{
    __shared__ float sq[512];
    __shared__ float msqs[16];
    const int tid = threadIdx.x;      // j*16 + u
    const int b   = blockIdx.x;
    const int bg  = b >> 5, blb = b & 31;

    const float* base = SP + ((size_t)bg*NCHUNK*32 + blb)*512 + tid;
    float sum = 0.f;
#pragma unroll 8
    for (int ch = 0; ch < NCHUNK; ++ch) sum += base[(size_t)ch * 32 * 512];
    float s = (mode == 0) ? sum * (1.f/32.f) : sum;   // iter0: c_ij = 1/32 exactly

    sq[tid] = s * s;
    __syncthreads();
    if (tid < 16) {
        float m = 0.f;
#pragma unroll
        for (int j2 = 0; j2 < 32; ++j2) m += sq[j2*16 + tid];
        msqs[tid] = m;
    }
    __syncthreads();
    const float msq = msqs[tid & 15];
    const float mag = sqrtf(msq + 1e-8f);
    const float v   = (msq / (1.f + msq)) * (s / (mag + 1e-8f));
    const size_t idx = (size_t)b*512 + tid;
    if (mode == 0)      { v0buf[idx] = v; v01buf[idx] = v; }
    else if (mode == 1) { v01buf[idx] = v0buf[idx] + v; }   // b2 uses v0+v1
    else                { outp[idx] = v; }
}

extern "C" void kernel_launch(void* const* d_in, const int* in_sizes, int n_in,
                              void* d_out, int out_size, void* d_ws, size_t ws_size,
                              hipStream_t stream)
{
    const float* x = (const float*)d_in[0];
    const float* W = (const float*)d_in[1];

    float* SP  = (float*)d_ws;
    float* v0  = (float*)((char*)d_ws + (size_t)NBG * NCHUNK * 32 * 512 * 4);
    float* v01 = v0 + 65536;
    float* out = (float*)d_out;

    dim3 grid(512), blk(512);
    route_kernel<0><<<grid, blk, LDS_SZ, stream>>>(x, W, nullptr, SP);
    squash_kernel  <<<128, 512, 0, stream>>>(SP, v0, v01, out, 0);
    route_kernel<1><<<grid, blk, LDS_SZ, stream>>>(x, W, v01, SP);
    squash_kernel  <<<128, 512, 0, stream>>>(SP, v0, v01, out, 1);
    route_kernel<1><<<grid, blk, LDS_SZ, stream>>>(x, W, v01, SP);
    squash_kernel  <<<128, 512, 0, stream>>>(SP, v0, v01, out, 2);
}